// Round 6
// baseline (261.624 us; speedup 1.0000x reference)
//
#include <hip/hip_runtime.h>
#include <math.h>

// Problem constants (B=2, N=1024, DE=1024, H=16, DH=64 complex dims/head)
#define BB      2
#define NN      1024
#define DE_     1024
#define HH      16
#define TWO_DK  2048
#define PK      4194304     // B*H*N*128 packed elements per q/k/v stream
#define TBLR    1092        // per-head table entries: dt in [-64, 1028)

typedef float f32x4  __attribute__((ext_vector_type(4)));
typedef short bf16x8 __attribute__((ext_vector_type(8)));

__device__ __forceinline__ short f2bf(float f) {
    unsigned u = __float_as_uint(f);
    unsigned r = (u + 0x7fffu + ((u >> 16) & 1u)) >> 16;   // RNE
    return (short)r;
}

#define GLDS16(g, l) __builtin_amdgcn_global_load_lds(                        \
    (const __attribute__((address_space(1))) unsigned int*)(g),               \
    (__attribute__((address_space(3))) unsigned int*)(l), 16, 0, 0)
#define GLDS4(g, l) __builtin_amdgcn_global_load_lds(                         \
    (const __attribute__((address_space(1))) unsigned int*)(g),               \
    (__attribute__((address_space(3))) unsigned int*)(l), 4, 0, 0)

// ---------------------------------------------------------------------------
// prep: z=0..2 transpose Wq/Wk/Wv -> wt[n][k] bf16; z=3,bx<16 transpose Wo;
//       z=3,bx>=16 decay tables; z=4 x fp32->bf16 (8 elems/thread).
// ---------------------------------------------------------------------------
__global__ __launch_bounds__(256) void prep(
    const float* __restrict__ x,
    const float* __restrict__ Wq, const float* __restrict__ Wk,
    const float* __restrict__ Wv, const float* __restrict__ Wo,
    const float* __restrict__ mu_raw, const float* __restrict__ sigma_raw,
    const float* __restrict__ eta_raw, const float* __restrict__ gamma_raw,
    short* __restrict__ xb, short* __restrict__ wt, short* __restrict__ wot,
    float4* __restrict__ tbl) {
    const int z = blockIdx.z;
    if (z == 4) {
        const int flat = blockIdx.y * 32 + blockIdx.x;
        const int i = (flat * 256 + threadIdx.x) * 8;
        float4 v0 = *(const float4*)&x[i];
        float4 v1 = *(const float4*)&x[i + 4];
        short4 o0, o1;
        o0.x = f2bf(v0.x); o0.y = f2bf(v0.y); o0.z = f2bf(v0.z); o0.w = f2bf(v0.w);
        o1.x = f2bf(v1.x); o1.y = f2bf(v1.y); o1.z = f2bf(v1.z); o1.w = f2bf(v1.w);
        *(short4*)&xb[i] = o0; *(short4*)&xb[i + 4] = o1;
        return;
    }
    if (z == 3 && blockIdx.x >= 16) {
        const int idx = blockIdx.y * 16 + (blockIdx.x - 16);
        if (idx >= 80) return;
        const int h = idx / 5, rb = idx % 5;
        const int r = rb * 256 + threadIdx.x;
        if (r >= TBLR) return;
        const float mu = 1.f / (1.f + expf(-mu_raw[h])) + 1e-4f;
        const float Ac = log1pf(expf(sigma_raw[h])) / (2.f * mu);
        const float Cc = log1pf(expf(eta_raw[h])) + log1pf(expf(gamma_raw[h]));
        const float arg = fminf(fmaxf(-mu * (float)(r - 64), -30.f), 0.f);
        const float E   = expf(arg);
        const float V   = fmaf(Ac, 1.f - E * E, Cc);
        tbl[h * TBLR + r] = make_float4(E, 1.f / V, -32.f * logf(V), 0.f);
        return;
    }
    const float* in; short* out; int R, C;
    if (z < 3) { if (blockIdx.y >= 16) return;
                 in = (z == 0) ? Wq : (z == 1) ? Wk : Wv;
                 out = wt + (size_t)z * 2097152; R = 1024; C = 2048; }
    else       { in = Wo; out = wot; R = 2048; C = 1024; }
    __shared__ float t[64][65];
    const int c0 = blockIdx.x * 64, r0 = blockIdx.y * 64;
    const int tr = threadIdx.x >> 4, tc4 = (threadIdx.x & 15) * 4;
#pragma unroll
    for (int s = 0; s < 4; ++s) {
        const int r = tr + s * 16;
        float4 v = *(const float4*)&in[(size_t)(r0 + r) * C + c0 + tc4];
        t[r][tc4] = v.x; t[r][tc4 + 1] = v.y; t[r][tc4 + 2] = v.z; t[r][tc4 + 3] = v.w;
    }
    __syncthreads();
#pragma unroll
    for (int s = 0; s < 4; ++s) {
        const int oc = tr + s * 16;
        short4 o;
        o.x = f2bf(t[tc4 + 0][oc]); o.y = f2bf(t[tc4 + 1][oc]);
        o.z = f2bf(t[tc4 + 2][oc]); o.w = f2bf(t[tc4 + 3][oc]);
        *(short4*)&out[(size_t)(c0 + oc) * R + r0 + tc4] = o;
    }
}

// ---------------------------------------------------------------------------
// QKV GEMM with fused RoPE rotation + norms. Block: 128 m-rows x 256 paired
// cols = (2 heads) x (128 dd = re||im). z selects stream (q/k/v).
// Wave w: rows (w>>1)*64..+63, head hsel=(w&1) (128 dd cols). acc[4][8].
// Epilogue z<2: in-register rotation (lane holds re at jb, im at jb+4 of the
// SAME complex elem), norms via quad shuffle, bf16 packed store.
// Epilogue z==2: transposed V store (8B short4 over n).
// ---------------------------------------------------------------------------
__global__ __launch_bounds__(256) void gemm_qkv_rot(
    const short* __restrict__ A, const short* __restrict__ wt,
    const float* __restrict__ omega,
    short* __restrict__ qb, short* __restrict__ kb, short* __restrict__ vtb,
    float* __restrict__ qn_, float* __restrict__ kn_) {
    __shared__ __align__(16) short As[128 * 64];   // 16 KB
    __shared__ __align__(16) short Bs[256 * 64];   // 32 KB
    const int tid = threadIdx.x;
    const int m0  = blockIdx.x * 128;
    const int c0  = blockIdx.y * 128;              // re-col base (2 heads)
    const short* W = wt + (size_t)blockIdx.z * 2097152;

    // A staging meta (rows 0..127, width 64, XOR chunk swizzle)
    const short* aP[4]; int aOff[4];
#pragma unroll
    for (int i = 0; i < 4; ++i) {
        const int c = i * 256 + tid, row = c >> 3;
        const int src = ((c & 7) ^ (row & 7)) << 3;
        aP[i] = A + (size_t)(m0 + row) * 1024 + src;
        aOff[i] = c * 8;
    }
    // B staging meta (rows j 0..255 -> W col = im*1024 + c0 + head*64 + d)
    const short* bP[8]; int bOff[8];
#pragma unroll
    for (int i = 0; i < 8; ++i) {
        const int c = i * 256 + tid, j = c >> 3;
        const int src  = ((c & 7) ^ (j & 7)) << 3;
        const int head = j >> 7, dd = j & 127, im = dd >> 6, d = dd & 63;
        bP[i] = W + (size_t)(im * 1024 + c0 + head * 64 + d) * 1024 + src;
        bOff[i] = c * 8;
    }

    const int lane = tid & 63, w = tid >> 6;
    const int wr = (w >> 1) * 64, hsel = w & 1, jwb = hsel * 128;
    const int fr = lane & 15;
    const int fo = (lane >> 4) << 3;
    const int sw = (fr & 7) << 3;

    f32x4 acc[4][8];
#pragma unroll
    for (int a = 0; a < 4; ++a)
#pragma unroll
        for (int jb = 0; jb < 8; ++jb) acc[a][jb] = (f32x4){0.f, 0.f, 0.f, 0.f};

    for (int k0 = 0; k0 < 1024; k0 += 64) {
#pragma unroll
        for (int i = 0; i < 4; ++i) GLDS16(aP[i] + k0, &As[aOff[i]]);
#pragma unroll
        for (int i = 0; i < 8; ++i) GLDS16(bP[i] + k0, &Bs[bOff[i]]);
        __syncthreads();
#pragma unroll
        for (int ks = 0; ks < 64; ks += 32) {
            bf16x8 af[4], bf[8];
#pragma unroll
            for (int a = 0; a < 4; ++a)
                af[a] = *(const bf16x8*)&As[(wr + a * 16 + fr) * 64 + ((ks + fo) ^ sw)];
#pragma unroll
            for (int jb = 0; jb < 8; ++jb)
                bf[jb] = *(const bf16x8*)&Bs[(jwb + jb * 16 + fr) * 64 + ((ks + fo) ^ sw)];
#pragma unroll
            for (int a = 0; a < 4; ++a)
#pragma unroll
                for (int jb = 0; jb < 8; ++jb)
                    acc[a][jb] = __builtin_amdgcn_mfma_f32_16x16x32_bf16(
                        af[a], bf[jb], acc[a][jb], 0, 0, 0);
        }
        __syncthreads();
    }

    const int cq  = (lane >> 4) * 4, l15 = lane & 15;
    const int h   = (c0 >> 6) + hsel;
    const int bh  = (m0 >> 10) * 16 + h;
    const int n2b = (m0 & 1023) + wr + cq;

    if (blockIdx.z == 2) {
        // V: transposed store vt[(bh*128+dd)][n], 8B over 4 n-consecutive regs
#pragma unroll
        for (int a = 0; a < 4; ++a) {
#pragma unroll
            for (int jb = 0; jb < 8; ++jb) {
                const int dd = jb * 16 + l15;
                short4 o;
                o.x = f2bf(acc[a][jb][0]); o.y = f2bf(acc[a][jb][1]);
                o.z = f2bf(acc[a][jb][2]); o.w = f2bf(acc[a][jb][3]);
                *(short4*)&vtb[((size_t)bh * 128 + dd) * 1024 + n2b + a * 16] = o;
            }
        }
        return;
    }
    float* nout = (blockIdx.z == 0) ? qn_ : kn_;
    short* obuf = (blockIdx.z == 0) ? qb  : kb;
    // norms (from exact f32 pre-rotation; rotation preserves them)
#pragma unroll
    for (int a = 0; a < 4; ++a) {
        float ns[4] = {0.f, 0.f, 0.f, 0.f};
#pragma unroll
        for (int jb = 0; jb < 8; ++jb)
#pragma unroll
            for (int r = 0; r < 4; ++r)
                ns[r] = fmaf(acc[a][jb][r], acc[a][jb][r], ns[r]);
#pragma unroll
        for (int m2 = 1; m2 < 16; m2 <<= 1)
#pragma unroll
            for (int r = 0; r < 4; ++r) ns[r] += __shfl_xor(ns[r], m2);
        if (l15 == 0)
#pragma unroll
            for (int r = 0; r < 4; ++r)
                nout[(size_t)bh * 1024 + n2b + a * 16 + r] = ns[r];
    }
    // rotation + packed bf16 store
#pragma unroll
    for (int jb = 0; jb < 4; ++jb) {
        const int d = jb * 16 + l15;
        const float om = (d < 32) ? omega[h * 32 + d] : -omega[h * 32 + d - 32];
#pragma unroll
        for (int a = 0; a < 4; ++a) {
#pragma unroll
            for (int r = 0; r < 4; ++r) {
                const int n2 = n2b + a * 16 + r;
                float sn, cs;
                sincosf((float)n2 * om, &sn, &cs);
                const float re = acc[a][jb][r], im = acc[a][jb + 4][r];
                short* orow = obuf + ((size_t)bh * 1024 + n2) * 128;
                orow[d]      = f2bf(re * cs - im * sn);
                orow[64 + d] = f2bf(re * sn + im * cs);
            }
        }
    }
}

// ---------------------------------------------------------------------------
// MFMA flash attention, software-pipelined: double-buffered K/V/tables staged
// via global_load_lds for tile jt+1 BEFORE computing tile jt (1 barrier/tile).
// 4 waves, 64 Q-rows of one (b,h); Q-frags in registers.
// ---------------------------------------------------------------------------
__global__ __launch_bounds__(256) void attn_mfma(
    const short* __restrict__ qr, const short* __restrict__ kr,
    const short* __restrict__ vt,
    const float* __restrict__ qn, const float* __restrict__ kn,
    const float4* __restrict__ tbl,
    const float* __restrict__ tau_p, const float* __restrict__ nu_raw,
    short* __restrict__ y) {
    __shared__ __align__(16) short Ks[2][64 * 128];
    __shared__ __align__(16) short Vs[2][128 * 64];
    __shared__ __align__(16) short Ps[64 * 72];
    __shared__ __align__(16) float4 sT[2][128];
    __shared__ float sKn[2][64];

    const int bh = blockIdx.y;
    const int h  = bh & 15;
    const int it = (bh & 16) ? (15 - (int)blockIdx.x) : (int)blockIdx.x;
    const int i0 = it * 64;
    const int tid  = threadIdx.x;
    const int lane = tid & 63, w = tid >> 6;
    const int quad = lane >> 4, l15 = lane & 15;

    const float nu     = log1pf(expf(nu_raw[h]));
    const float coef   = -0.5f * tau_p[h] * (nu + 64.0f);
    const float inv_nu = 1.f / nu;

    const short* Qb  = qr + (size_t)bh * NN * 128;
    const short* Kb  = kr + (size_t)bh * NN * 128;
    const short* Vtb = vt + (size_t)bh * 128 * NN;

#define STAGE(JT, P) do {                                                     \
        const int j0_ = (JT) * 64, dt0_ = i0 - j0_;                           \
        _Pragma("unroll")                                                     \
        for (int i_ = 0; i_ < 4; ++i_) {                                      \
            const int c_ = i_ * 256 + tid, row_ = c_ >> 4;                    \
            const int src_ = ((c_ & 15) ^ (row_ & 7)) * 8;                    \
            GLDS16(Kb + (size_t)(j0_ + row_) * 128 + src_, &Ks[P][c_ * 8]);   \
        }                                                                     \
        _Pragma("unroll")                                                     \
        for (int i_ = 0; i_ < 4; ++i_) {                                      \
            const int c_ = i_ * 256 + tid, d_ = c_ >> 3;                      \
            const int src_ = ((c_ & 7) ^ (d_ & 7)) * 8;                       \
            GLDS16(Vtb + (size_t)d_ * NN + j0_ + src_, &Vs[P][c_ * 8]);       \
        }                                                                     \
        if (w == 0) {                                                         \
            GLDS16(tbl + h * TBLR + 1 + dt0_ + lane, &sT[P][lane]);           \
            GLDS16(tbl + h * TBLR + 65 + dt0_ + lane, &sT[P][64 + lane]);     \
        } else if (w == 1) {                                                  \
            GLDS4(kn + (size_t)bh * NN + j0_ + lane, &sKn[P][lane]);          \
        }                                                                     \
    } while (0)

    // Q-fragments in registers
    bf16x8 qf[4];
    const int arow = i0 + w * 16 + l15;
#pragma unroll
    for (int ks = 0; ks < 4; ++ks)
        qf[ks] = *(const bf16x8*)&Qb[(size_t)arow * 128 + ks * 32 + quad * 8];

    float mrow[4], lrow[4];
    f32x4 o[8];
#pragma unroll
    for (int r = 0; r < 4; ++r) { mrow[r] = -INFINITY; lrow[r] = 0.f; }
#pragma unroll
    for (int s = 0; s < 8; ++s) o[s] = (f32x4){0.f, 0.f, 0.f, 0.f};
    float qn4[4];
#pragma unroll
    for (int r = 0; r < 4; ++r)
        qn4[r] = qn[(size_t)bh * NN + i0 + w * 16 + quad * 4 + r];

    STAGE(0, 0);
    __syncthreads();

    for (int jt = 0; jt <= it; ++jt) {
        const int p = jt & 1;
        if (jt < it) STAGE(jt + 1, 1 - p);   // async prefetch; drained at barrier

        // -------- S = Q @ K^T --------
        f32x4 sAcc[4];
#pragma unroll
        for (int s = 0; s < 4; ++s) sAcc[s] = (f32x4){0.f, 0.f, 0.f, 0.f};
#pragma unroll
        for (int ks = 0; ks < 4; ++ks) {
#pragma unroll
            for (int s = 0; s < 4; ++s) {
                const int brow = s * 16 + l15;
                bf16x8 bK = *(const bf16x8*)&Ks[p][brow * 128 +
                                                  (((ks * 4 + quad) ^ (brow & 7)) * 8)];
                sAcc[s] = __builtin_amdgcn_mfma_f32_16x16x32_bf16(qf[ks], bK, sAcc[s], 0, 0, 0);
            }
        }

        // -------- softmax on C-layout --------
        float al[4];
#pragma unroll
        for (int r = 0; r < 4; ++r) {
            const int row = w * 16 + quad * 4 + r;
            float lg[4];
            float mx = -INFINITY;
#pragma unroll
            for (int s = 0; s < 4; ++s) {
                const int col = s * 16 + l15;
                const float4 T = sT[p][row - col + 63];
                const float sv = sAcc[s][r];
                const float maha =
                    fmaxf(fmaf(T.x * T.x, sKn[p][col], qn4[r]) - 2.f * T.x * sv, 0.f) * T.y;
                float v = fmaf(coef, __logf(fmaf(maha, inv_nu, 1.f)), T.z);
                if (jt == it && col > row) v = -INFINITY;
                lg[s] = v;
                mx = fmaxf(mx, v);
            }
            mx = fmaxf(mx, __shfl_xor(mx, 1));
            mx = fmaxf(mx, __shfl_xor(mx, 2));
            mx = fmaxf(mx, __shfl_xor(mx, 4));
            mx = fmaxf(mx, __shfl_xor(mx, 8));
            const float mn = fmaxf(mrow[r], mx);
            const float a_ = __expf(mrow[r] - mn);
            float rs = 0.f;
#pragma unroll
            for (int s = 0; s < 4; ++s) {
                const float pv = __expf(lg[s] - mn);
                Ps[row * 72 + s * 16 + l15] = f2bf(pv);
                rs += pv;
            }
            rs += __shfl_xor(rs, 1);
            rs += __shfl_xor(rs, 2);
            rs += __shfl_xor(rs, 4);
            rs += __shfl_xor(rs, 8);
            lrow[r] = fmaf(lrow[r], a_, rs);
            mrow[r] = mn;
            al[r] = a_;
        }
#pragma unroll
        for (int s = 0; s < 8; ++s)
#pragma unroll
            for (int r = 0; r < 4; ++r) o[s][r] *= al[r];

        // -------- O += P @ V (Ps rows own-wave only) --------
#pragma unroll
        for (int jc = 0; jc < 2; ++jc) {
            bf16x8 aP = *(const bf16x8*)&Ps[(w * 16 + l15) * 72 + jc * 32 + quad * 8];
#pragma unroll
            for (int sub = 0; sub < 8; ++sub) {
                const int d = sub * 16 + l15;
                bf16x8 bV = *(const bf16x8*)&Vs[p][d * 64 + (((jc * 4 + quad) ^ (d & 7)) * 8)];
                o[sub] = __builtin_amdgcn_mfma_f32_16x16x32_bf16(aP, bV, o[sub], 0, 0, 0);
            }
        }
        if (jt < it) __syncthreads();   // buf[p] reads done + prefetch drained
    }
#undef STAGE

    // -------- epilogue: O/l -> bf16 packed y --------
#pragma unroll
    for (int r = 0; r < 4; ++r) {
        const float inv = 1.f / lrow[r];
        const size_t base = ((size_t)bh * NN + i0 + w * 16 + quad * 4 + r) * 128;
#pragma unroll
        for (int sub = 0; sub < 8; ++sub)
            y[base + sub * 16 + l15] = f2bf(o[sub][r] * inv);
    }
}

// ---------------------------------------------------------------------------
// Output GEMM: out[2048][1024] = y @ Wo. 64x128 tiles, grid (32,8) = 256
// blocks (1/CU), BK=64, direct f32 stores. A remapped from packed y.
// ---------------------------------------------------------------------------
__global__ __launch_bounds__(256) void gemm_out64(
    const short* __restrict__ yb, const short* __restrict__ wot,
    float* __restrict__ out) {
    __shared__ __align__(16) short As[64 * 64];    // 8 KB
    __shared__ __align__(16) short Bs[128 * 64];   // 16 KB
    const int tid = threadIdx.x;
    const int m0  = blockIdx.x * 64;
    const int n0  = blockIdx.y * 128;
    const int bb  = m0 >> 10;

    int aPre[2], aOff[2];
#pragma unroll
    for (int i = 0; i < 2; ++i) {
        const int c = i * 256 + tid, row = c >> 3;
        const int src = ((c & 7) ^ (row & 7)) << 3;
        aPre[i] = ((m0 & 1023) + row) * 128 + src;
        aOff[i] = c * 8;
    }
    const short* bP[4]; int bOff[4];
#pragma unroll
    for (int i = 0; i < 4; ++i) {
        const int c = i * 256 + tid, row = c >> 3;
        const int src = ((c & 7) ^ (row & 7)) << 3;
        bP[i] = wot + (size_t)(n0 + row) * 2048 + src;
        bOff[i] = c * 8;
    }

    const int lane = tid & 63, w = tid >> 6;
    const int wr = (w >> 1) * 32, wc = (w & 1) * 64;
    const int fr = lane & 15;
    const int fo = (lane >> 4) << 3;
    const int sw = (fr & 7) << 3;

    f32x4 acc[2][4];
#pragma unroll
    for (int a = 0; a < 2; ++a)
#pragma unroll
        for (int b = 0; b < 4; ++b) acc[a][b] = (f32x4){0.f, 0.f, 0.f, 0.f};

    for (int k0 = 0; k0 < 2048; k0 += 64) {
        const int hh = (k0 >> 6) & 15, im = k0 >> 10;
        const short* ab = yb + ((size_t)(bb * 16 + hh) << 17) + im * 64;
#pragma unroll
        for (int i = 0; i < 2; ++i) GLDS16(ab + aPre[i], &As[aOff[i]]);
#pragma unroll
        for (int i = 0; i < 4; ++i) GLDS16(bP[i] + k0, &Bs[bOff[i]]);
        __syncthreads();
#pragma unroll
        for (int ks = 0; ks < 64; ks += 32) {
            bf16x8 af[2], bf[4];
#pragma unroll
            for (int a = 0; a < 2; ++a)
                af[a] = *(const bf16x8*)&As[(wr + a * 16 + fr) * 64 + ((ks + fo) ^ sw)];
#pragma unroll
            for (int b = 0; b < 4; ++b)
                bf[b] = *(const bf16x8*)&Bs[(wc + b * 16 + fr) * 64 + ((ks + fo) ^ sw)];
#pragma unroll
            for (int a = 0; a < 2; ++a)
#pragma unroll
                for (int b = 0; b < 4; ++b)
                    acc[a][b] = __builtin_amdgcn_mfma_f32_16x16x32_bf16(
                        af[a], bf[b], acc[a][b], 0, 0, 0);
        }
        __syncthreads();
    }

    const int cq = (lane >> 4) * 4, l15 = lane & 15;
#pragma unroll
    for (int a = 0; a < 2; ++a)
#pragma unroll
        for (int b = 0; b < 4; ++b)
#pragma unroll
            for (int r = 0; r < 4; ++r)
                out[(size_t)(m0 + wr + a * 16 + cq + r) * 1024 +
                    (n0 + wc + b * 16 + l15)] = acc[a][b][r];
}

// ---------------------------------------------------------------------------
extern "C" void kernel_launch(void* const* d_in, const int* in_sizes, int n_in,
                              void* d_out, int out_size, void* d_ws, size_t ws_size,
                              hipStream_t stream) {
    const float* x         = (const float*)d_in[0];
    const float* Wq        = (const float*)d_in[1];
    const float* Wk        = (const float*)d_in[2];
    const float* Wv        = (const float*)d_in[3];
    const float* Wo        = (const float*)d_in[4];
    const float* omega     = (const float*)d_in[5];
    const float* mu_raw    = (const float*)d_in[6];
    const float* sigma_raw = (const float*)d_in[7];
    const float* eta_raw   = (const float*)d_in[8];
    const float* gamma_raw = (const float*)d_in[9];
    const float* tau       = (const float*)d_in[10];
    const float* nu_raw    = (const float*)d_in[11];
    float* out = (float*)d_out;

    // ws layout: qb | kb | vtb (bf16, PK each) | qn | kn (f32) | tbl (float4)
    //            | wot | wt x3 | xb (bf16).   yb aliases wt.
    short*  qb  = (short*)d_ws;
    short*  kb  = qb + PK;
    short*  vtb = kb + PK;
    float*  qn  = (float*)(vtb + PK);
    float*  kn  = qn + 32768;
    float4* tbl = (float4*)(kn + 32768);
    short*  wot = (short*)(tbl + HH * TBLR);
    short*  wt  = wot + 2097152;
    short*  xb  = wt + 3 * 2097152;
    short*  yb  = wt;                               // alias

    prep<<<dim3(32, 32, 5), 256, 0, stream>>>(
        x, Wq, Wk, Wv, Wo, mu_raw, sigma_raw, eta_raw, gamma_raw,
        xb, wt, wot, tbl);
    gemm_qkv_rot<<<dim3(16, 8, 3), 256, 0, stream>>>(
        xb, wt, omega, qb, kb, vtb, qn, kn);
    attn_mfma<<<dim3(16, 32), 256, 0, stream>>>(
        qb, kb, vtb, qn, kn, tbl, tau, nu_raw, yb);
    gemm_out64<<<dim3(32, 8), 256, 0, stream>>>(yb, wot, out);
}

// Round 7
// 218.510 us; speedup vs baseline: 1.1973x; 1.1973x over previous
//
#include <hip/hip_runtime.h>
#include <math.h>

// Problem constants (B=2, N=1024, DE=1024, H=16, DH=64 complex dims/head)
#define BB      2
#define NN      1024
#define DE_     1024
#define HH      16
#define TWO_DK  2048
#define PK      4194304     // B*H*N*128 packed elements per q/k/v stream
#define TBLR    1092        // per-head table entries: dt in [-64, 1028)

typedef float f32x4  __attribute__((ext_vector_type(4)));
typedef short bf16x8 __attribute__((ext_vector_type(8)));

__device__ __forceinline__ short f2bf(float f) {
    unsigned u = __float_as_uint(f);
    unsigned r = (u + 0x7fffu + ((u >> 16) & 1u)) >> 16;   // RNE
    return (short)r;
}

#define GLDS16(g, l) __builtin_amdgcn_global_load_lds(                        \
    (const __attribute__((address_space(1))) unsigned int*)(g),               \
    (__attribute__((address_space(3))) unsigned int*)(l), 16, 0, 0)
#define GLDS4(g, l) __builtin_amdgcn_global_load_lds(                         \
    (const __attribute__((address_space(1))) unsigned int*)(g),               \
    (__attribute__((address_space(3))) unsigned int*)(l), 4, 0, 0)

// ---------------------------------------------------------------------------
// prep: z=0..2 transpose Wq/Wk/Wv -> wt[n][k] bf16; z=3,bx<16 transpose Wo;
//       z=3,bx>=16 decay tables; z=4 x fp32->bf16.
// ---------------------------------------------------------------------------
__global__ __launch_bounds__(256) void prep(
    const float* __restrict__ x,
    const float* __restrict__ Wq, const float* __restrict__ Wk,
    const float* __restrict__ Wv, const float* __restrict__ Wo,
    const float* __restrict__ mu_raw, const float* __restrict__ sigma_raw,
    const float* __restrict__ eta_raw, const float* __restrict__ gamma_raw,
    short* __restrict__ xb, short* __restrict__ wt, short* __restrict__ wot,
    float4* __restrict__ tbl) {
    const int z = blockIdx.z;
    if (z == 4) {
        const int flat = blockIdx.y * 32 + blockIdx.x;
        const int i = (flat * 256 + threadIdx.x) * 8;
        float4 v0 = *(const float4*)&x[i];
        float4 v1 = *(const float4*)&x[i + 4];
        short4 o0, o1;
        o0.x = f2bf(v0.x); o0.y = f2bf(v0.y); o0.z = f2bf(v0.z); o0.w = f2bf(v0.w);
        o1.x = f2bf(v1.x); o1.y = f2bf(v1.y); o1.z = f2bf(v1.z); o1.w = f2bf(v1.w);
        *(short4*)&xb[i] = o0; *(short4*)&xb[i + 4] = o1;
        return;
    }
    if (z == 3 && blockIdx.x >= 16) {
        const int idx = blockIdx.y * 16 + (blockIdx.x - 16);
        if (idx >= 80) return;
        const int h = idx / 5, rb = idx % 5;
        const int r = rb * 256 + threadIdx.x;
        if (r >= TBLR) return;
        const float mu = 1.f / (1.f + expf(-mu_raw[h])) + 1e-4f;
        const float Ac = log1pf(expf(sigma_raw[h])) / (2.f * mu);
        const float Cc = log1pf(expf(eta_raw[h])) + log1pf(expf(gamma_raw[h]));
        const float arg = fminf(fmaxf(-mu * (float)(r - 64), -30.f), 0.f);
        const float E   = expf(arg);
        const float V   = fmaf(Ac, 1.f - E * E, Cc);
        tbl[h * TBLR + r] = make_float4(E, 1.f / V, -32.f * logf(V), 0.f);
        return;
    }
    const float* in; short* out; int R, C;
    if (z < 3) { if (blockIdx.y >= 16) return;
                 in = (z == 0) ? Wq : (z == 1) ? Wk : Wv;
                 out = wt + (size_t)z * 2097152; R = 1024; C = 2048; }
    else       { in = Wo; out = wot; R = 2048; C = 1024; }
    __shared__ float t[64][65];
    const int c0 = blockIdx.x * 64, r0 = blockIdx.y * 64;
    const int tr = threadIdx.x >> 4, tc4 = (threadIdx.x & 15) * 4;
#pragma unroll
    for (int s = 0; s < 4; ++s) {
        const int r = tr + s * 16;
        float4 v = *(const float4*)&in[(size_t)(r0 + r) * C + c0 + tc4];
        t[r][tc4] = v.x; t[r][tc4 + 1] = v.y; t[r][tc4 + 2] = v.z; t[r][tc4 + 3] = v.w;
    }
    __syncthreads();
#pragma unroll
    for (int s = 0; s < 4; ++s) {
        const int oc = tr + s * 16;
        short4 o;
        o.x = f2bf(t[tc4 + 0][oc]); o.y = f2bf(t[tc4 + 1][oc]);
        o.z = f2bf(t[tc4 + 2][oc]); o.w = f2bf(t[tc4 + 3][oc]);
        *(short4*)&out[(size_t)(c0 + oc) * R + r0 + tc4] = o;
    }
}

// ---------------------------------------------------------------------------
// QKV GEMM + fused RoPE rotation/norms. 128x128 tile, grid (16 m, 16 head, 3 z)
// = 768 blocks (3/CU). Block's 128 cols = head by's full re||im, LDS B rows
// interleaved per 16-col subtile: rows [32t+16u .. +15] = u?im:re, d=16t..16t+15.
// => acc[a][2p] / acc[a][2p+1] hold the re/im pair of the SAME complex elem in
// the same lane -> in-register rotation (32 hw __sincosf / lane).
// z==2: V stored transposed via 8B short4.
// ---------------------------------------------------------------------------
__global__ __launch_bounds__(256) void gemm_qkv_rot2(
    const short* __restrict__ A, const short* __restrict__ wt,
    const float* __restrict__ omega,
    short* __restrict__ qb, short* __restrict__ kb, short* __restrict__ vtb,
    float* __restrict__ qn_, float* __restrict__ kn_) {
    __shared__ __align__(16) short As[128 * 64];   // 16 KB
    __shared__ __align__(16) short Bs[128 * 64];   // 16 KB
    __shared__ float sN[2][128];
    const int tid = threadIdx.x;
    const int m0  = blockIdx.x * 128;
    const int h   = blockIdx.y;
    const short* W = wt + (size_t)blockIdx.z * 2097152;

    const short* aP[4]; const short* bP[4]; int ldsoff[4];
#pragma unroll
    for (int i = 0; i < 4; ++i) {
        const int c   = i * 256 + tid;
        const int row = c >> 3;
        const int src = ((c & 7) ^ (row & 7)) << 3;
        ldsoff[i] = c * 8;
        aP[i] = A + (size_t)(m0 + row) * 1024 + src;
        // B remap: row j -> t=j>>5, u=(j>>4)&1, dcol = t*16 + (j&15)
        const int t_ = row >> 5, u_ = (row >> 4) & 1, dcol = t_ * 16 + (row & 15);
        bP[i] = W + (size_t)(u_ * 1024 + h * 64 + dcol) * 1024 + src;
    }

    const int lane = tid & 63, w = tid >> 6;
    const int wr = (w >> 1) * 64, hsel = w & 1, wc = hsel * 64;
    const int fr = lane & 15;
    const int fo = (lane >> 4) << 3;
    const int sw = (fr & 7) << 3;

    f32x4 acc[4][4];
#pragma unroll
    for (int a = 0; a < 4; ++a)
#pragma unroll
        for (int b = 0; b < 4; ++b) acc[a][b] = (f32x4){0.f, 0.f, 0.f, 0.f};

    for (int k0 = 0; k0 < 1024; k0 += 64) {
#pragma unroll
        for (int i = 0; i < 4; ++i) GLDS16(aP[i] + k0, &As[ldsoff[i]]);
#pragma unroll
        for (int i = 0; i < 4; ++i) GLDS16(bP[i] + k0, &Bs[ldsoff[i]]);
        __syncthreads();
#pragma unroll
        for (int ks = 0; ks < 64; ks += 32) {
            bf16x8 af[4], bf[4];
#pragma unroll
            for (int a = 0; a < 4; ++a)
                af[a] = *(const bf16x8*)&As[(wr + a * 16 + fr) * 64 + ((ks + fo) ^ sw)];
#pragma unroll
            for (int b = 0; b < 4; ++b)
                bf[b] = *(const bf16x8*)&Bs[(wc + b * 16 + fr) * 64 + ((ks + fo) ^ sw)];
#pragma unroll
            for (int a = 0; a < 4; ++a)
#pragma unroll
                for (int b = 0; b < 4; ++b)
                    acc[a][b] = __builtin_amdgcn_mfma_f32_16x16x32_bf16(
                        af[a], bf[b], acc[a][b], 0, 0, 0);
        }
        __syncthreads();
    }

    // C/D layout: col=lane&15, row=(lane>>4)*4+reg  [m89]
    const int cq = (lane >> 4) * 4, l15 = lane & 15;
    const int bh  = (m0 >> 10) * 16 + h;
    const int nb0 = (m0 & 1023) + wr + cq;

    if (blockIdx.z == 2) {
        // V: transposed store vt[(bh*128+dd)][n], 8B over 4 n-consecutive regs
#pragma unroll
        for (int a = 0; a < 4; ++a) {
#pragma unroll
            for (int b = 0; b < 4; ++b) {
                const int cl = wc + b * 16;            // u=(cl>>4)&1, t=cl>>5
                const int dd = ((cl >> 4) & 1) * 64 + (cl >> 5) * 16 + l15;
                short4 o;
                o.x = f2bf(acc[a][b][0]); o.y = f2bf(acc[a][b][1]);
                o.z = f2bf(acc[a][b][2]); o.w = f2bf(acc[a][b][3]);
                *(short4*)&vtb[((size_t)bh * 128 + dd) * 1024 + nb0 + a * 16] = o;
            }
        }
        return;
    }
    float* nout = (blockIdx.z == 0) ? qn_ : kn_;
    short* obuf = (blockIdx.z == 0) ? qb  : kb;

    // norms: this wave covers 32 of the 64 complex dims; pair with wave w^1
#pragma unroll
    for (int a = 0; a < 4; ++a) {
        float ns[4] = {0.f, 0.f, 0.f, 0.f};
#pragma unroll
        for (int b = 0; b < 4; ++b)
#pragma unroll
            for (int r = 0; r < 4; ++r)
                ns[r] = fmaf(acc[a][b][r], acc[a][b][r], ns[r]);
#pragma unroll
        for (int m2 = 1; m2 < 16; m2 <<= 1)
#pragma unroll
            for (int r = 0; r < 4; ++r) ns[r] += __shfl_xor(ns[r], m2);
        if (l15 == 0)
#pragma unroll
            for (int r = 0; r < 4; ++r) sN[hsel][wr + a * 16 + cq + r] = ns[r];
    }
    __syncthreads();
    if (tid < 128)
        nout[(size_t)bh * 1024 + (m0 & 1023) + tid] = sN[0][tid] + sN[1][tid];

    // rotation + packed bf16 store (pairs: b=2p re, b=2p+1 im; same d, same lane)
#pragma unroll
    for (int p = 0; p < 2; ++p) {
        const int d = (hsel * 2 + p) * 16 + l15;
        const float om = (d < 32) ? omega[h * 32 + d] : -omega[h * 32 + d - 32];
#pragma unroll
        for (int a = 0; a < 4; ++a) {
#pragma unroll
            for (int r = 0; r < 4; ++r) {
                const int n2 = nb0 + a * 16 + r;
                float sn, cs;
                __sincosf((float)n2 * om, &sn, &cs);
                const float re = acc[a][2 * p][r], im = acc[a][2 * p + 1][r];
                short* orow = obuf + ((size_t)bh * 1024 + n2) * 128;
                orow[d]      = f2bf(re * cs - im * sn);
                orow[64 + d] = f2bf(re * sn + im * cs);
            }
        }
    }
}

// ---------------------------------------------------------------------------
// MFMA flash attention, software-pipelined (double-buffered K/V/tables,
// 1 barrier/tile). 4 waves, 64 Q-rows of one (b,h); Q-frags in registers.
// ---------------------------------------------------------------------------
__global__ __launch_bounds__(256) void attn_mfma(
    const short* __restrict__ qr, const short* __restrict__ kr,
    const short* __restrict__ vt,
    const float* __restrict__ qn, const float* __restrict__ kn,
    const float4* __restrict__ tbl,
    const float* __restrict__ tau_p, const float* __restrict__ nu_raw,
    short* __restrict__ y) {
    __shared__ __align__(16) short Ks[2][64 * 128];
    __shared__ __align__(16) short Vs[2][128 * 64];
    __shared__ __align__(16) short Ps[64 * 72];
    __shared__ __align__(16) float4 sT[2][128];
    __shared__ float sKn[2][64];

    const int bh = blockIdx.y;
    const int h  = bh & 15;
    const int it = (bh & 16) ? (15 - (int)blockIdx.x) : (int)blockIdx.x;
    const int i0 = it * 64;
    const int tid  = threadIdx.x;
    const int lane = tid & 63, w = tid >> 6;
    const int quad = lane >> 4, l15 = lane & 15;

    const float nu     = log1pf(expf(nu_raw[h]));
    const float coef   = -0.5f * tau_p[h] * (nu + 64.0f);
    const float inv_nu = 1.f / nu;

    const short* Qb  = qr + (size_t)bh * NN * 128;
    const short* Kb  = kr + (size_t)bh * NN * 128;
    const short* Vtb = vt + (size_t)bh * 128 * NN;

#define STAGE(JT, P) do {                                                     \
        const int j0_ = (JT) * 64, dt0_ = i0 - j0_;                           \
        _Pragma("unroll")                                                     \
        for (int i_ = 0; i_ < 4; ++i_) {                                      \
            const int c_ = i_ * 256 + tid, row_ = c_ >> 4;                    \
            const int src_ = ((c_ & 15) ^ (row_ & 7)) * 8;                    \
            GLDS16(Kb + (size_t)(j0_ + row_) * 128 + src_, &Ks[P][c_ * 8]);   \
        }                                                                     \
        _Pragma("unroll")                                                     \
        for (int i_ = 0; i_ < 4; ++i_) {                                      \
            const int c_ = i_ * 256 + tid, d_ = c_ >> 3;                      \
            const int src_ = ((c_ & 7) ^ (d_ & 7)) * 8;                       \
            GLDS16(Vtb + (size_t)d_ * NN + j0_ + src_, &Vs[P][c_ * 8]);       \
        }                                                                     \
        if (w == 0) {                                                         \
            GLDS16(tbl + h * TBLR + 1 + dt0_ + lane, &sT[P][lane]);           \
            GLDS16(tbl + h * TBLR + 65 + dt0_ + lane, &sT[P][64 + lane]);     \
        } else if (w == 1) {                                                  \
            GLDS4(kn + (size_t)bh * NN + j0_ + lane, &sKn[P][lane]);          \
        }                                                                     \
    } while (0)

    bf16x8 qf[4];
    const int arow = i0 + w * 16 + l15;
#pragma unroll
    for (int ks = 0; ks < 4; ++ks)
        qf[ks] = *(const bf16x8*)&Qb[(size_t)arow * 128 + ks * 32 + quad * 8];

    float mrow[4], lrow[4];
    f32x4 o[8];
#pragma unroll
    for (int r = 0; r < 4; ++r) { mrow[r] = -INFINITY; lrow[r] = 0.f; }
#pragma unroll
    for (int s = 0; s < 8; ++s) o[s] = (f32x4){0.f, 0.f, 0.f, 0.f};
    float qn4[4];
#pragma unroll
    for (int r = 0; r < 4; ++r)
        qn4[r] = qn[(size_t)bh * NN + i0 + w * 16 + quad * 4 + r];

    STAGE(0, 0);
    __syncthreads();

    for (int jt = 0; jt <= it; ++jt) {
        const int p = jt & 1;
        if (jt < it) STAGE(jt + 1, 1 - p);   // async prefetch; drained at barrier

        f32x4 sAcc[4];
#pragma unroll
        for (int s = 0; s < 4; ++s) sAcc[s] = (f32x4){0.f, 0.f, 0.f, 0.f};
#pragma unroll
        for (int ks = 0; ks < 4; ++ks) {
#pragma unroll
            for (int s = 0; s < 4; ++s) {
                const int brow = s * 16 + l15;
                bf16x8 bK = *(const bf16x8*)&Ks[p][brow * 128 +
                                                  (((ks * 4 + quad) ^ (brow & 7)) * 8)];
                sAcc[s] = __builtin_amdgcn_mfma_f32_16x16x32_bf16(qf[ks], bK, sAcc[s], 0, 0, 0);
            }
        }

        float al[4];
#pragma unroll
        for (int r = 0; r < 4; ++r) {
            const int row = w * 16 + quad * 4 + r;
            float lg[4];
            float mx = -INFINITY;
#pragma unroll
            for (int s = 0; s < 4; ++s) {
                const int col = s * 16 + l15;
                const float4 T = sT[p][row - col + 63];
                const float sv = sAcc[s][r];
                const float maha =
                    fmaxf(fmaf(T.x * T.x, sKn[p][col], qn4[r]) - 2.f * T.x * sv, 0.f) * T.y;
                float v = fmaf(coef, __logf(fmaf(maha, inv_nu, 1.f)), T.z);
                if (jt == it && col > row) v = -INFINITY;
                lg[s] = v;
                mx = fmaxf(mx, v);
            }
            mx = fmaxf(mx, __shfl_xor(mx, 1));
            mx = fmaxf(mx, __shfl_xor(mx, 2));
            mx = fmaxf(mx, __shfl_xor(mx, 4));
            mx = fmaxf(mx, __shfl_xor(mx, 8));
            const float mn = fmaxf(mrow[r], mx);
            const float a_ = __expf(mrow[r] - mn);
            float rs = 0.f;
#pragma unroll
            for (int s = 0; s < 4; ++s) {
                const float pv = __expf(lg[s] - mn);
                Ps[row * 72 + s * 16 + l15] = f2bf(pv);
                rs += pv;
            }
            rs += __shfl_xor(rs, 1);
            rs += __shfl_xor(rs, 2);
            rs += __shfl_xor(rs, 4);
            rs += __shfl_xor(rs, 8);
            lrow[r] = fmaf(lrow[r], a_, rs);
            mrow[r] = mn;
            al[r] = a_;
        }
#pragma unroll
        for (int s = 0; s < 8; ++s)
#pragma unroll
            for (int r = 0; r < 4; ++r) o[s][r] *= al[r];

#pragma unroll
        for (int jc = 0; jc < 2; ++jc) {
            bf16x8 aP = *(const bf16x8*)&Ps[(w * 16 + l15) * 72 + jc * 32 + quad * 8];
#pragma unroll
            for (int sub = 0; sub < 8; ++sub) {
                const int d = sub * 16 + l15;
                bf16x8 bV = *(const bf16x8*)&Vs[p][d * 64 + (((jc * 4 + quad) ^ (d & 7)) * 8)];
                o[sub] = __builtin_amdgcn_mfma_f32_16x16x32_bf16(aP, bV, o[sub], 0, 0, 0);
            }
        }
        if (jt < it) __syncthreads();
    }
#undef STAGE

#pragma unroll
    for (int r = 0; r < 4; ++r) {
        const float inv = 1.f / lrow[r];
        const size_t base = ((size_t)bh * NN + i0 + w * 16 + quad * 4 + r) * 128;
#pragma unroll
        for (int sub = 0; sub < 8; ++sub)
            y[base + sub * 16 + l15] = f2bf(o[sub][r] * inv);
    }
}

// ---------------------------------------------------------------------------
// Output GEMM: out[2048][1024] = y @ Wo. 64x64 tiles, grid (32,16) = 512
// blocks (2/CU), BK=64, direct f32 stores. A remapped from packed y.
// ---------------------------------------------------------------------------
__global__ __launch_bounds__(256) void gemm_out64(
    const short* __restrict__ yb, const short* __restrict__ wot,
    float* __restrict__ out) {
    __shared__ __align__(16) short As[64 * 64];    // 8 KB
    __shared__ __align__(16) short Bs[64 * 64];    // 8 KB
    const int tid = threadIdx.x;
    const int m0  = blockIdx.x * 64;
    const int n0  = blockIdx.y * 64;
    const int bb  = m0 >> 10;

    int aPre[2], aOff[2]; const short* bP[2];
#pragma unroll
    for (int i = 0; i < 2; ++i) {
        const int c = i * 256 + tid, row = c >> 3;
        const int src = ((c & 7) ^ (row & 7)) << 3;
        aPre[i] = ((m0 & 1023) + row) * 128 + src;
        bP[i] = wot + (size_t)(n0 + row) * 2048 + src;
        aOff[i] = c * 8;
    }

    const int lane = tid & 63, w = tid >> 6;
    const int wr = (w >> 1) * 32, wc = (w & 1) * 32;
    const int fr = lane & 15;
    const int fo = (lane >> 4) << 3;
    const int sw = (fr & 7) << 3;

    f32x4 acc[2][2];
#pragma unroll
    for (int a = 0; a < 2; ++a)
#pragma unroll
        for (int b = 0; b < 2; ++b) acc[a][b] = (f32x4){0.f, 0.f, 0.f, 0.f};

    for (int k0 = 0; k0 < 2048; k0 += 64) {
        const int hh = (k0 >> 6) & 15, im = k0 >> 10;
        const short* ab = yb + ((size_t)(bb * 16 + hh) << 17) + im * 64;
#pragma unroll
        for (int i = 0; i < 2; ++i) GLDS16(ab + aPre[i], &As[aOff[i]]);
#pragma unroll
        for (int i = 0; i < 2; ++i) GLDS16(bP[i] + k0, &Bs[aOff[i]]);
        __syncthreads();
#pragma unroll
        for (int ks = 0; ks < 64; ks += 32) {
            bf16x8 af[2], bf[2];
#pragma unroll
            for (int a = 0; a < 2; ++a)
                af[a] = *(const bf16x8*)&As[(wr + a * 16 + fr) * 64 + ((ks + fo) ^ sw)];
#pragma unroll
            for (int b = 0; b < 2; ++b)
                bf[b] = *(const bf16x8*)&Bs[(wc + b * 16 + fr) * 64 + ((ks + fo) ^ sw)];
#pragma unroll
            for (int a = 0; a < 2; ++a)
#pragma unroll
                for (int b = 0; b < 2; ++b)
                    acc[a][b] = __builtin_amdgcn_mfma_f32_16x16x32_bf16(
                        af[a], bf[b], acc[a][b], 0, 0, 0);
        }
        __syncthreads();
    }

    const int cq = (lane >> 4) * 4, l15 = lane & 15;
#pragma unroll
    for (int a = 0; a < 2; ++a)
#pragma unroll
        for (int b = 0; b < 2; ++b)
#pragma unroll
            for (int r = 0; r < 4; ++r)
                out[(size_t)(m0 + wr + a * 16 + cq + r) * 1024 +
                    (n0 + wc + b * 16 + l15)] = acc[a][b][r];
}

// ---------------------------------------------------------------------------
extern "C" void kernel_launch(void* const* d_in, const int* in_sizes, int n_in,
                              void* d_out, int out_size, void* d_ws, size_t ws_size,
                              hipStream_t stream) {
    const float* x         = (const float*)d_in[0];
    const float* Wq        = (const float*)d_in[1];
    const float* Wk        = (const float*)d_in[2];
    const float* Wv        = (const float*)d_in[3];
    const float* Wo        = (const float*)d_in[4];
    const float* omega     = (const float*)d_in[5];
    const float* mu_raw    = (const float*)d_in[6];
    const float* sigma_raw = (const float*)d_in[7];
    const float* eta_raw   = (const float*)d_in[8];
    const float* gamma_raw = (const float*)d_in[9];
    const float* tau       = (const float*)d_in[10];
    const float* nu_raw    = (const float*)d_in[11];
    float* out = (float*)d_out;

    short*  qb  = (short*)d_ws;
    short*  kb  = qb + PK;
    short*  vtb = kb + PK;
    float*  qn  = (float*)(vtb + PK);
    float*  kn  = qn + 32768;
    float4* tbl = (float4*)(kn + 32768);
    short*  wot = (short*)(tbl + HH * TBLR);
    short*  wt  = wot + 2097152;
    short*  xb  = wt + 3 * 2097152;
    short*  yb  = wt;                               // alias (wt dead after qkv)

    prep<<<dim3(32, 32, 5), 256, 0, stream>>>(
        x, Wq, Wk, Wv, Wo, mu_raw, sigma_raw, eta_raw, gamma_raw,
        xb, wt, wot, tbl);
    gemm_qkv_rot2<<<dim3(16, 16, 3), 256, 0, stream>>>(
        xb, wt, omega, qb, kb, vtb, qn, kn);
    attn_mfma<<<dim3(16, 32), 256, 0, stream>>>(
        qb, kb, vtb, qn, kn, tbl, tau, nu_raw, yb);
    gemm_out64<<<dim3(32, 16), 256, 0, stream>>>(yb, wot, out);
}